// Round 14
// baseline (717.034 us; speedup 1.0000x reference)
//
#include <hip/hip_runtime.h>
#include <hip/hip_bf16.h>

#define NL 6
#define DM 768
#define DI 1536
#define DS 16
#define NRANK 48
#define DBC 80
#define BATCH 2
#define SEQ 1024
#define NTOK (BATCH*SEQ)
#define NCHUNK 64
#define CHLEN 16
#define XKS 8
#define XKC (DI/XKS)

typedef __attribute__((ext_vector_type(8))) short short8;
typedef __attribute__((ext_vector_type(8))) unsigned short ushort8v;
typedef __attribute__((ext_vector_type(4))) float f32x4;
typedef __attribute__((ext_vector_type(4))) unsigned short ushort4v;

__device__ inline unsigned short f2bf(float f) {
  union { float f; unsigned u; } x; x.f = f;
  unsigned r = x.u + 0x7FFF + ((x.u >> 16) & 1);
  return (unsigned short)(r >> 16);
}
__device__ inline float bf2f(unsigned short s) {
  union { unsigned u; float f; } x; x.u = ((unsigned)s) << 16;
  return x.f;
}

__device__ inline void gl_lds16(const unsigned short* g, unsigned short* l) {
  __builtin_amdgcn_global_load_lds(
      (const __attribute__((address_space(1))) unsigned int*)(g),
      (__attribute__((address_space(3))) unsigned int*)(l),
      16, 0, 0);
}

// convert ranges, unit = 8 elements; ADA tail unit = 1 element
#define V_X   (NTOK * DM / 8)
#define V_INW (NL * 2 * DI * DM / 8)
#define V_OUW (NL * DM * DI / 8)
#define V_XPW (NL * DBC * DI / 8)
#define V_DTW (NL * DI * 64 / 8)
#define V_NA  (NL * DI * DS / 8)
#define V_DTA (NTOK * 64 / 8)
#define V_ADA (NL * BATCH * 2 * DM)
#define V_ALL (V_X + V_INW + V_OUW + V_XPW + V_DTW + V_NA + V_DTA + V_ADA)

__device__ inline ushort8v cvt8v(f32x4 a, f32x4 b) {
  union { ushort8v u8; __hip_bfloat162 h[4]; } u;
  float2 p;
  p.x = a[0]; p.y = a[1]; u.h[0] = __float22bfloat162_rn(p);
  p.x = a[2]; p.y = a[3]; u.h[1] = __float22bfloat162_rn(p);
  p.x = b[0]; p.y = b[1]; u.h[2] = __float22bfloat162_rn(p);
  p.x = b[2]; p.y = b[3]; u.h[3] = __float22bfloat162_rn(p);
  return u.u8;
}
__device__ inline void cvt8_store(const float* s, unsigned short* d, int i) {
  f32x4 a = ((const f32x4*)s)[i * 2];
  f32x4 b = ((const f32x4*)s)[i * 2 + 1];
  ((ushort8v*)d)[i] = cvt8v(a, b);
}

// streaming conversions + adaln matvec tail
__global__ __launch_bounds__(256) void cvt_k(
    const float* __restrict__ x, const float* __restrict__ inw,
    const float* __restrict__ ouw, const float* __restrict__ xpw,
    const float* __restrict__ dtpw, const float* __restrict__ alog,
    const float* __restrict__ cond, const float* __restrict__ adaw,
    const float* __restrict__ adab,
    unsigned short* __restrict__ xb, unsigned short* __restrict__ inwb,
    unsigned short* __restrict__ ouwb, unsigned short* __restrict__ xpwb,
    unsigned short* __restrict__ dtwb, float* __restrict__ na,
    unsigned short* __restrict__ dtA, float* __restrict__ ss) {
  for (int i = blockIdx.x * 256 + threadIdx.x; i < V_ALL; i += gridDim.x * 256) {
    int k = i;
    if (k < V_X) { cvt8_store(x, xb, k); continue; }
    k -= V_X;
    if (k < V_INW) { cvt8_store(inw, inwb, k); continue; }
    k -= V_INW;
    if (k < V_OUW) { cvt8_store(ouw, ouwb, k); continue; }
    k -= V_OUW;
    if (k < V_XPW) { cvt8_store(xpw, xpwb, k); continue; }
    k -= V_XPW;
    if (k < V_DTW) {
      int col8 = (k & 7) * 8;
      int row = k >> 3;
      ushort8v u8;
      if (col8 < NRANK) {
        const float* src = dtpw + (size_t)row * NRANK + col8;
        f32x4 a = *(const f32x4*)src;
        f32x4 b = *(const f32x4*)(src + 4);
        u8 = cvt8v(a, b);
      } else {
        u8 = (ushort8v){0,0,0,0,0,0,0,0};
      }
      *(ushort8v*)&dtwb[(size_t)row * 64 + col8] = u8;
      continue;
    }
    k -= V_DTW;
    if (k < V_NA) {
      f32x4 a = ((const f32x4*)alog)[k * 2];
      f32x4 b = ((const f32x4*)alog)[k * 2 + 1];
      f32x4 ra, rb;
#pragma unroll
      for (int e = 0; e < 4; e++) { ra[e] = -__expf(a[e]); rb[e] = -__expf(b[e]); }
      ((f32x4*)na)[k * 2] = ra;
      ((f32x4*)na)[k * 2 + 1] = rb;
      continue;
    }
    k -= V_NA;
    if (k < V_DTA) {
      ((ushort8v*)dtA)[k] = (ushort8v){0,0,0,0,0,0,0,0};
      continue;
    }
    k -= V_DTA;
    {
      int e = k % (2 * DM);
      int b = (k / (2 * DM)) % BATCH;
      int l = k / (BATCH * 2 * DM);
      const float* c = cond + b * 128;
      const float* wp = adaw + ((size_t)l * (2 * DM) + e) * 128;
      float s = adab[l * (2 * DM) + e];
      for (int kk = 0; kk < 128; kk++) s = fmaf(c[kk], wp[kk], s);
      ss[k] = s;
    }
  }
}

// ---------------------------------------------------------------------------
// 64x128-tile bf16 GEMM -> bf16 out (in_proj). 3-stage counted-vmcnt pipeline.
// Grid (N/128, M/64) -> 768 blocks for in_proj (3 blocks/CU).
// ---------------------------------------------------------------------------
__global__ __launch_bounds__(256) void bt64x128_k(
    const unsigned short* __restrict__ A, int lda,
    const unsigned short* __restrict__ W, int ldw,
    unsigned short* __restrict__ C, int ldc,
    int K) {
  __shared__ __align__(16) unsigned short As[3][64 * 32];
  __shared__ __align__(16) unsigned short Ws[3][128 * 32];
  const int tid = threadIdx.x;
  const int bm = blockIdx.y * 64;
  const int bn = blockIdx.x * 128;
  const int lane = tid & 63;
  const int wv = tid >> 6;
  const int wm = (wv >> 1) * 32;
  const int wn = (wv & 1) * 64;
  const int fr = lane & 15;
  const int fs = lane >> 4;

  const int r0 = tid >> 2;
  const int s0 = (tid & 3) ^ (r0 & 3);

  const unsigned short* gA  = A + (size_t)(bm + r0) * lda + s0 * 8;
  const unsigned short* gW0 = W + (size_t)(bn + r0) * ldw + s0 * 8;
  const unsigned short* gW1 = W + (size_t)(bn + r0 + 64) * ldw + s0 * 8;

  f32x4 acc[2][4];
#pragma unroll
  for (int i = 0; i < 2; i++)
#pragma unroll
    for (int j = 0; j < 4; j++) acc[i][j] = (f32x4){0.f, 0.f, 0.f, 0.f};

  const int nk = K >> 5;
  gl_lds16(gA, &As[0][0] + tid * 8);
  gl_lds16(gW0, &Ws[0][0] + tid * 8);
  gl_lds16(gW1, &Ws[0][2048] + tid * 8);
  if (nk > 1) {
    gl_lds16(gA + 32, &As[1][0] + tid * 8);
    gl_lds16(gW0 + 32, &Ws[1][0] + tid * 8);
    gl_lds16(gW1 + 32, &Ws[1][2048] + tid * 8);
  }

  for (int kk = 0; kk < nk; kk++) {
    const int b = kk % 3;
    if (kk + 2 < nk) {
      const int k0 = (kk + 2) * 32;
      const int nb = (kk + 2) % 3;
      gl_lds16(gA + k0, &As[nb][0] + tid * 8);
      gl_lds16(gW0 + k0, &Ws[nb][0] + tid * 8);
      gl_lds16(gW1 + k0, &Ws[nb][2048] + tid * 8);
    }
    const int ahead = (nk - 1 - kk >= 2) ? 2 : (nk - 1 - kk);
    if (ahead == 2)      asm volatile("s_waitcnt vmcnt(6)" : : : "memory");
    else if (ahead == 1) asm volatile("s_waitcnt vmcnt(3)" : : : "memory");
    else                 asm volatile("s_waitcnt vmcnt(0)" : : : "memory");
    __builtin_amdgcn_s_barrier();
    __builtin_amdgcn_sched_barrier(0);

    short8 af[2], bf[4];
#pragma unroll
    for (int i = 0; i < 2; i++) {
      int rowa = wm + i * 16 + fr;
      af[i] = *(const short8*)&As[b][rowa * 32 + ((fs ^ (rowa & 3)) * 8)];
    }
#pragma unroll
    for (int j = 0; j < 4; j++) {
      int rowb = wn + j * 16 + fr;
      bf[j] = *(const short8*)&Ws[b][rowb * 32 + ((fs ^ (rowb & 3)) * 8)];
    }
#pragma unroll
    for (int i = 0; i < 2; i++)
#pragma unroll
      for (int j = 0; j < 4; j++)
        acc[i][j] = __builtin_amdgcn_mfma_f32_16x16x32_bf16(af[i], bf[j], acc[i][j], 0, 0, 0);

    __builtin_amdgcn_s_barrier();
  }

#pragma unroll
  for (int i = 0; i < 2; i++) {
#pragma unroll
    for (int j = 0; j < 4; j++) {
#pragma unroll
      for (int r = 0; r < 4; r++) {
        int row = bm + wm + i * 16 + fs * 4 + r;
        int col = bn + wn + j * 16 + fr;
        C[(size_t)row * ldc + col] = f2bf(acc[i][j][r]);
      }
    }
  }
}

// ---------------------------------------------------------------------------
// 64x64-tile bf16 GEMM, 3-stage pipeline.
// EPI 1: softplus(v+bias)->bf16. EPI 3: fp32 partial at [z*NTOK+row] (split-K).
// ---------------------------------------------------------------------------
template<int EPI>
__global__ __launch_bounds__(256) void bt64_k(
    const unsigned short* __restrict__ A, int lda,
    const unsigned short* __restrict__ W, int ldw,
    void* __restrict__ Cv, int ldc,
    int K,
    const float* __restrict__ bias) {
  __shared__ __align__(16) unsigned short As[3][64 * 32];
  __shared__ __align__(16) unsigned short Ws[3][64 * 32];
  const int tid = threadIdx.x;
  const int bm = blockIdx.y * 64;
  const int bn = blockIdx.x * 64;
  const int kz = (EPI == 3) ? blockIdx.z : 0;
  const int lane = tid & 63;
  const int wv = tid >> 6;
  const int wm = (wv >> 1) * 32;
  const int wn = (wv & 1) * 32;
  const int fr = lane & 15;
  const int fs = lane >> 4;

  const int r0 = tid >> 2;
  const int s0 = (tid & 3) ^ (r0 & 3);

  const unsigned short* gA = A + (size_t)(bm + r0) * lda + kz * K + s0 * 8;
  const unsigned short* gW = W + (size_t)(bn + r0) * ldw + kz * K + s0 * 8;

  f32x4 acc[2][2];
#pragma unroll
  for (int i = 0; i < 2; i++)
#pragma unroll
    for (int j = 0; j < 2; j++) acc[i][j] = (f32x4){0.f, 0.f, 0.f, 0.f};

  const int nk = K >> 5;
  gl_lds16(gA, &As[0][0] + tid * 8);
  gl_lds16(gW, &Ws[0][0] + tid * 8);
  if (nk > 1) {
    gl_lds16(gA + 32, &As[1][0] + tid * 8);
    gl_lds16(gW + 32, &Ws[1][0] + tid * 8);
  }

  for (int kk = 0; kk < nk; kk++) {
    const int b = kk % 3;
    if (kk + 2 < nk) {
      const int k0 = (kk + 2) * 32;
      const int nb = (kk + 2) % 3;
      gl_lds16(gA + k0, &As[nb][0] + tid * 8);
      gl_lds16(gW + k0, &Ws[nb][0] + tid * 8);
    }
    const int ahead = (nk - 1 - kk >= 2) ? 2 : (nk - 1 - kk);
    if (ahead == 2)      asm volatile("s_waitcnt vmcnt(4)" : : : "memory");
    else if (ahead == 1) asm volatile("s_waitcnt vmcnt(2)" : : : "memory");
    else                 asm volatile("s_waitcnt vmcnt(0)" : : : "memory");
    __builtin_amdgcn_s_barrier();
    __builtin_amdgcn_sched_barrier(0);

    short8 af[2], bf[2];
#pragma unroll
    for (int i = 0; i < 2; i++) {
      int rowa = wm + i * 16 + fr;
      af[i] = *(const short8*)&As[b][rowa * 32 + ((fs ^ (rowa & 3)) * 8)];
      int rowb = wn + i * 16 + fr;
      bf[i] = *(const short8*)&Ws[b][rowb * 32 + ((fs ^ (rowb & 3)) * 8)];
    }
#pragma unroll
    for (int i = 0; i < 2; i++)
#pragma unroll
      for (int j = 0; j < 2; j++)
        acc[i][j] = __builtin_amdgcn_mfma_f32_16x16x32_bf16(af[i], bf[j], acc[i][j], 0, 0, 0);

    __builtin_amdgcn_s_barrier();
  }

#pragma unroll
  for (int i = 0; i < 2; i++) {
#pragma unroll
    for (int j = 0; j < 2; j++) {
#pragma unroll
      for (int r = 0; r < 4; r++) {
        int row = bm + wm + i * 16 + fs * 4 + r;
        int col = bn + wn + j * 16 + fr;
        float v = acc[i][j][r];
        if (EPI == 1) {
          float xv = v + bias[col];
          float sp = (xv > 20.f) ? xv : log1pf(__expf(xv));
          ((unsigned short*)Cv)[(size_t)row * ldc + col] = f2bf(sp);
        }
        if (EPI == 3) {
          ((float*)Cv)[((size_t)kz * NTOK + row) * ldc + col] = v;
        }
      }
    }
  }
}

// ---------------------------------------------------------------------------
// x_proj split-K, bf16 in, bf16 partials out
// ---------------------------------------------------------------------------
__global__ __launch_bounds__(256) void xp_k(
    const unsigned short* __restrict__ A,
    const unsigned short* __restrict__ W,
    unsigned short* __restrict__ part) {
  __shared__ __align__(16) unsigned short As[64][40];
  __shared__ __align__(16) unsigned short Ws[80][40];
  const int tid = threadIdx.x;
  const int ks = blockIdx.x;
  const int bm = blockIdx.y * 64;
  const int lane = tid & 63;
  const int wv = tid >> 6;
  const int fr = lane & 15;
  const int fs = lane >> 4;
  const int fk = fs * 8;

  const int ar = tid >> 2;
  const int ac = (tid & 3) * 8;
  const int k0base = ks * XKC;

  const unsigned short* gA  = A + (size_t)(bm + ar) * DI + k0base + ac;
  const unsigned short* gW0 = W + (size_t)ar * DI + k0base + ac;
  const unsigned short* gW1 = W + (size_t)(64 + ar) * DI + k0base + ac;

  f32x4 acc[5];
#pragma unroll
  for (int n = 0; n < 5; n++) acc[n] = (f32x4){0.f, 0.f, 0.f, 0.f};

  short8 aA, w0A, w1A;
  aA = *(const short8*)(gA);
  w0A = *(const short8*)(gW0);
  if (tid < 64) w1A = *(const short8*)(gW1);

  const int nk = XKC / 32;
  for (int kk = 0; kk < nk; kk++) {
    __syncthreads();
    *(short8*)&As[ar][ac] = aA;
    *(short8*)&Ws[ar][ac] = w0A;
    if (tid < 64) *(short8*)&Ws[64 + ar][ac] = w1A;
    __syncthreads();

    if (kk + 1 < nk) {
      const int k0 = (kk + 1) * 32;
      aA = *(const short8*)(gA + k0);
      w0A = *(const short8*)(gW0 + k0);
      if (tid < 64) w1A = *(const short8*)(gW1 + k0);
    }

    short8 af = *(const short8*)&As[wv * 16 + fr][fk];
#pragma unroll
    for (int n = 0; n < 5; n++) {
      short8 bf = *(const short8*)&Ws[n * 16 + fr][fk];
      acc[n] = __builtin_amdgcn_mfma_f32_16x16x32_bf16(af, bf, acc[n], 0, 0, 0);
    }
  }

#pragma unroll
  for (int n = 0; n < 5; n++) {
#pragma unroll
    for (int r = 0; r < 4; r++) {
      int row = bm + wv * 16 + fs * 4 + r;
      part[((size_t)ks * NTOK + row) * DBC + n * 16 + fr] = f2bf(acc[n][r]);
    }
  }
}

// sum XKS bf16 partials -> dtA bf16 (cols 0..47) / bc bf16 (cols 48..79 -> 0..31)
__global__ __launch_bounds__(256) void xp_reduce_k(const unsigned short* __restrict__ part,
                                                   unsigned short* __restrict__ dtA,
                                                   unsigned short* __restrict__ bc) {
  int i = blockIdx.x * 256 + threadIdx.x;
  const ushort4v* p4 = (const ushort4v*)part;
  const int stride4 = NTOK * DBC / 4;
  float s0 = 0.f, s1 = 0.f, s2 = 0.f, s3 = 0.f;
#pragma unroll
  for (int ks = 0; ks < XKS; ks++) {
    ushort4v v = p4[(size_t)ks * stride4 + i];
    s0 += bf2f(v[0]); s1 += bf2f(v[1]); s2 += bf2f(v[2]); s3 += bf2f(v[3]);
  }
  ushort4v o;
  o[0] = f2bf(s0); o[1] = f2bf(s1); o[2] = f2bf(s2); o[3] = f2bf(s3);
  int c4 = (i * 4) % DBC;
  int m = (i * 4) / DBC;
  if (c4 < NRANK) {
    *(ushort4v*)&dtA[(size_t)m * 64 + c4] = o;
  } else {
    *(ushort4v*)&bc[(size_t)m * 32 + (c4 - NRANK)] = o;
  }
}

// depthwise causal conv(4) + bias + silu, register-carry, ushort2 vectorized
__global__ __launch_bounds__(256) void conv_silu_k(const unsigned short* __restrict__ xz,
                                                   const float* __restrict__ cw,
                                                   const float* __restrict__ cb,
                                                   unsigned short* __restrict__ xcb) {
  const int d0 = (blockIdx.x * 256 + threadIdx.x) * 2;
  const int l0 = blockIdx.y * 16;
  const int b = blockIdx.z;
  const size_t mbase = (size_t)b * SEQ;
  const float wa0 = cw[d0 * 4 + 0], wa1 = cw[d0 * 4 + 1];
  const float wa2 = cw[d0 * 4 + 2], wa3 = cw[d0 * 4 + 3];
  const float wb0 = cw[d0 * 4 + 4], wb1 = cw[d0 * 4 + 5];
  const float wb2 = cw[d0 * 4 + 6], wb3 = cw[d0 * 4 + 7];
  const float ba = cb[d0], bb = cb[d0 + 1];

  float a3 = 0.f, a2 = 0.f, a1 = 0.f, b3 = 0.f, b2 = 0.f, b1 = 0.f;
  if (l0 >= 3) { ushort2 u = *(const ushort2*)&xz[(mbase + l0 - 3) * (2 * DI) + d0]; a3 = bf2f(u.x); b3 = bf2f(u.y); }
  if (l0 >= 2) { ushort2 u = *(const ushort2*)&xz[(mbase + l0 - 2) * (2 * DI) + d0]; a2 = bf2f(u.x); b2 = bf2f(u.y); }
  if (l0 >= 1) { ushort2 u = *(const ushort2*)&xz[(mbase + l0 - 1) * (2 * DI) + d0]; a1 = bf2f(u.x); b1 = bf2f(u.y); }
#pragma unroll
  for (int t = 0; t < 16; t++) {
    const int l = l0 + t;
    ushort2 u = *(const ushort2*)&xz[(mbase + l) * (2 * DI) + d0];
    float ca = bf2f(u.x), cbv = bf2f(u.y);
    float sa = ba + wa0 * a3 + wa1 * a2 + wa2 * a1 + wa3 * ca;
    float sb = bb + wb0 * b3 + wb1 * b2 + wb2 * b1 + wb3 * cbv;
    float ra = sa / (1.f + __expf(-sa));
    float rb = sb / (1.f + __expf(-sb));
    ushort2 o; o.x = f2bf(ra); o.y = f2bf(rb);
    *(ushort2*)&xcb[(mbase + l) * DI + d0] = o;
    a3 = a2; a2 = a1; a1 = ca;
    b3 = b2; b2 = b1; b1 = cbv;
  }
}

// ---------------------------------------------------------------------------
// scan pass 1: bf16 inputs; outputs ch_pk (cumA|hloc bf16x2), yc_pk (yloc|cumdt)
// ---------------------------------------------------------------------------
__global__ __launch_bounds__(256) void scan1_k(const unsigned short* __restrict__ dt,
                                               const unsigned short* __restrict__ xc,
                                               const unsigned short* __restrict__ bc,
                                               const float* __restrict__ negA_l,
                                               unsigned int* __restrict__ ch_pk,
                                               unsigned int* __restrict__ yc_pk) {
  __shared__ float Bs[CHLEN][DS];
  __shared__ float Cs[CHLEN][DS];
  const int tid = threadIdx.x;
  const int j = blockIdx.x;
  const int cg = blockIdx.y;
  const int b = cg / 6;
  const int d = (cg % 6) * 256 + tid;
  const int c = b * DI + d;
  const int m0 = b * SEQ + j * CHLEN;

  for (int e = tid; e < CHLEN * 32; e += 256) {
    int row = e >> 5, col = e & 31;
    float v = bf2f(bc[(size_t)(m0 + row) * 32 + col]);
    if (col < DS) Bs[row][col] = v; else Cs[row][col - DS] = v;
  }

  float Av[DS];
  const float* na = negA_l + (size_t)d * DS;
#pragma unroll
  for (int s = 0; s < DS; s++) Av[s] = na[s];
  const float Av0 = Av[0];
  bool fast = true;
#pragma unroll
  for (int s = 0; s < DS; s++)
    fast = fast && (fabsf(Av[s] - (s + 1) * Av0) <= 1e-4f * (s + 1));

  float dts[CHLEN], xcs[CHLEN];
#pragma unroll
  for (int t = 0; t < CHLEN; t++) {
    dts[t] = bf2f(dt[(size_t)(m0 + t) * DI + d]);
    xcs[t] = bf2f(xc[(size_t)(m0 + t) * DI + d]);
  }
  __syncthreads();

  float h[DS];
#pragma unroll
  for (int s = 0; s < DS; s++) h[s] = 0.f;
  float cd = 0.f;

  for (int t = 0; t < CHLEN; t++) {
    float dtv = dts[t];
    cd += dtv;
    float dtx = dtv * xcs[t];
    float ysum = 0.f;
    if (fast) {
      float e1 = __expf(dtv * Av0);
      float dA = e1;
      h[0] = fmaf(dA, h[0], dtx * Bs[t][0]);
      ysum = fmaf(h[0], Cs[t][0], ysum);
#pragma unroll
      for (int s = 1; s < DS; s++) {
        dA *= e1;
        h[s] = fmaf(dA, h[s], dtx * Bs[t][s]);
        ysum = fmaf(h[s], Cs[t][s], ysum);
      }
    } else {
#pragma unroll
      for (int s = 0; s < DS; s++) {
        float dA = __expf(dtv * Av[s]);
        h[s] = fmaf(dA, h[s], dtx * Bs[t][s]);
        ysum = fmaf(h[s], Cs[t][s], ysum);
      }
    }
    yc_pk[(size_t)(m0 + t) * DI + d] =
        (unsigned int)f2bf(ysum) | ((unsigned int)f2bf(cd) << 16);
  }

  size_t base = ((size_t)j * (BATCH * DI) + c) * DS;
#pragma unroll
  for (int s = 0; s < DS; s++) {
    unsigned int pk = (unsigned int)f2bf(__expf(cd * Av[s]))
                    | ((unsigned int)f2bf(h[s]) << 16);
    ch_pk[base + s] = pk;
  }
}

// pass 2: sequential chunk combine, 8-wide load batching
__global__ __launch_bounds__(256) void scan2_k(const unsigned int* __restrict__ ch_pk,
                                               unsigned short* __restrict__ hin,
                                               float* __restrict__ states_out) {
  int idx = blockIdx.x * 256 + threadIdx.x;
  const int stride = BATCH * DI * DS;
  float h = 0.f;
  for (int g = 0; g < NCHUNK / 8; g++) {
    unsigned int pks[8];
#pragma unroll
    for (int u = 0; u < 8; u++)
      pks[u] = ch_pk[(size_t)(g * 8 + u) * stride + idx];
#pragma unroll
    for (int u = 0; u < 8; u++) {
      hin[(size_t)(g * 8 + u) * stride + idx] = f2bf(h);
      h = fmaf(bf2f((unsigned short)(pks[u] & 0xFFFF)), h,
               bf2f((unsigned short)(pks[u] >> 16)));
    }
  }
  states_out[idx] = h;
}

// pass 3: parallel fixup
__global__ __launch_bounds__(256) void scanfix_k(const unsigned int* __restrict__ yc_pk,
                                                 const unsigned short* __restrict__ xc,
                                                 const unsigned short* __restrict__ xz,
                                                 const unsigned short* __restrict__ bc,
                                                 const float* __restrict__ negA_l,
                                                 const float* __restrict__ Dsk,
                                                 const unsigned short* __restrict__ hin,
                                                 unsigned short* __restrict__ y) {
  int idx = blockIdx.x * 256 + threadIdx.x;
  int d = idx % DI;
  int m = idx / DI;
  int b = m / SEQ;
  int j = (m % SEQ) / CHLEN;
  unsigned int pk = yc_pk[idx];
  float yv = bf2f((unsigned short)(pk & 0xFFFF));
  float cd = bf2f((unsigned short)(pk >> 16));
  const f32x4* na4 = (const f32x4*)(negA_l + (size_t)d * DS);
  const ushort4v* cp4 = (const ushort4v*)(bc + (size_t)m * 32 + DS);
  const ushort4v* h4 = (const ushort4v*)(hin + ((size_t)j * (BATCH * DI) + (size_t)b * DI + d) * DS);
  float corr = 0.f;
#pragma unroll
  for (int q = 0; q < 4; q++) {
    f32x4 na = na4[q];
    ushort4v cp = cp4[q];
    ushort4v hh = h4[q];
#pragma unroll
    for (int e = 0; e < 4; e++)
      corr = fmaf(__expf(cd * na[e]) * bf2f(hh[e]), bf2f(cp[e]), corr);
  }
  yv += corr;
  float xv = bf2f(xc[idx]);
  float zv = bf2f(xz[(size_t)m * (2 * DI) + DI + d]);
  float sig = 1.f / (1.f + __expf(-zv));
  y[idx] = f2bf((yv + Dsk[d] * xv) * (zv * sig));
}

// LN. ADA=true: input = part[0]+part[1]+resid, LN -> LN_noaffine -> modulate.
template<bool ADA>
__global__ __launch_bounds__(256) void ln_k(const float* __restrict__ in,
                                            const float* __restrict__ resid,
                                            const float* __restrict__ w,
                                            const float* __restrict__ bb,
                                            const float* __restrict__ ss,
                                            float* __restrict__ out,
                                            unsigned short* __restrict__ outb) {
  __shared__ float red[8];
  const int row = blockIdx.x;
  const int bt = row / SEQ;
  const int tid = threadIdx.x;
  float v[3];
#pragma unroll
  for (int i = 0; i < 3; i++) {
    int c = tid + i * 256;
    if (ADA) {
      v[i] = in[(size_t)row * DM + c] + in[(size_t)(NTOK + row) * DM + c]
           + resid[(size_t)row * DM + c];
    } else {
      v[i] = in[(size_t)row * DM + c];
    }
  }
  float s1 = v[0] + v[1] + v[2];
  float s2 = v[0]*v[0] + v[1]*v[1] + v[2]*v[2];
#pragma unroll
  for (int o = 32; o > 0; o >>= 1) { s1 += __shfl_down(s1, o); s2 += __shfl_down(s2, o); }
  int wv = tid >> 6, ln = tid & 63;
  if (ln == 0) { red[wv*2] = s1; red[wv*2+1] = s2; }
  __syncthreads();
  s1 = red[0] + red[2] + red[4] + red[6];
  s2 = red[1] + red[3] + red[5] + red[7];
  float mu = s1 * (1.f / DM);
  float var = s2 * (1.f / DM) - mu * mu;
  float rs = rsqrtf(var + 1e-5f);
  float t[3];
#pragma unroll
  for (int i = 0; i < 3; i++) {
    int c = tid + i * 256;
    t[i] = (v[i] - mu) * rs * w[c] + bb[c];
  }
  if (!ADA) {
#pragma unroll
    for (int i = 0; i < 3; i++) out[(size_t)row * DM + tid + i * 256] = t[i];
    return;
  }
  __syncthreads();
  s1 = t[0] + t[1] + t[2];
  s2 = t[0]*t[0] + t[1]*t[1] + t[2]*t[2];
#pragma unroll
  for (int o = 32; o > 0; o >>= 1) { s1 += __shfl_down(s1, o); s2 += __shfl_down(s2, o); }
  if (ln == 0) { red[wv*2] = s1; red[wv*2+1] = s2; }
  __syncthreads();
  s1 = red[0] + red[2] + red[4] + red[6];
  s2 = red[1] + red[3] + red[5] + red[7];
  float mu2 = s1 * (1.f / DM);
  float var2 = s2 * (1.f / DM) - mu2 * mu2;
  float rs2 = rsqrtf(var2 + 1e-5f);
#pragma unroll
  for (int i = 0; i < 3; i++) {
    int c = tid + i * 256;
    float sc = ss[bt * (2 * DM) + c];
    float sh = ss[bt * (2 * DM) + DM + c];
    float r = (t[i] - mu2) * rs2 * (1.f + sc) + sh;
    out[(size_t)row * DM + c] = r;
    outb[(size_t)row * DM + c] = f2bf(r);
  }
}

extern "C" void kernel_launch(void* const* d_in, const int* in_sizes, int n_in,
                              void* d_out, int out_size, void* d_ws, size_t ws_size,
                              hipStream_t stream) {
  const float* x      = (const float*)d_in[0];
  const float* cond   = (const float*)d_in[1];
  const float* in_w   = (const float*)d_in[2];
  const float* conv_w = (const float*)d_in[3];
  const float* conv_b = (const float*)d_in[4];
  const float* xp_w   = (const float*)d_in[5];
  const float* dtp_w  = (const float*)d_in[6];
  const float* dtp_b  = (const float*)d_in[7];
  const float* A_log  = (const float*)d_in[8];
  const float* Dsk    = (const float*)d_in[9];
  const float* out_w  = (const float*)d_in[10];
  const float* norm_w = (const float*)d_in[11];
  const float* norm_b = (const float*)d_in[12];
  const float* ada_w  = (const float*)d_in[13];
  const float* ada_b  = (const float*)d_in[14];
  const float* fn_w   = (const float*)d_in[15];
  const float* fn_b   = (const float*)d_in[16];

  float* out_h = (float*)d_out;
  float* out_states = out_h + (size_t)NTOK * DM;

  float* p = (float*)d_ws;
  float* h_cur = p; p += (size_t)NTOK * DM;
  float* part2 = p; p += (size_t)2 * NTOK * DM;
  float* ss    = p; p += (size_t)NL * BATCH * 2 * DM;
  float* negA  = p; p += (size_t)NL * DI * DS;
  unsigned int* ch_pk = (unsigned int*)p; p += (size_t)NCHUNK * BATCH * DI * DS;
  unsigned int* yc_pk = (unsigned int*)p; p += (size_t)NTOK * DI;
  unsigned short* q = (unsigned short*)p;
  unsigned short* hin      = q; q += (size_t)NCHUNK * BATCH * DI * DS;
  unsigned short* in_w_bf  = q; q += (size_t)NL * 2 * DI * DM;
  unsigned short* out_w_bf = q; q += (size_t)NL * DM * DI;
  unsigned short* xp_w_bf  = q; q += (size_t)NL * DBC * DI;
  unsigned short* dtw_bf   = q; q += (size_t)NL * DI * 64;
  unsigned short* h_bf     = q; q += (size_t)NTOK * DM;
  unsigned short* xz_bf    = q; q += (size_t)NTOK * 2 * DI;
  unsigned short* xc_bf    = q; q += (size_t)NTOK * DI;
  unsigned short* dtb_bf   = q; q += (size_t)NTOK * DI;
  unsigned short* yb_bf    = q; q += (size_t)NTOK * DI;
  unsigned short* part_bf  = q; q += (size_t)XKS * NTOK * DBC;
  unsigned short* dtA_bf   = q; q += (size_t)NTOK * 64;
  unsigned short* bc_bf    = q; q += (size_t)NTOK * 32;

  cvt_k<<<4096, 256, 0, stream>>>(x, in_w, out_w, xp_w, dtp_w, A_log,
                                  cond, ada_w, ada_b,
                                  h_bf, in_w_bf, out_w_bf, xp_w_bf, dtw_bf,
                                  negA, dtA_bf, ss);

  for (int l = 0; l < NL; l++) {
    // in_proj -> xz (bf16), 64x128 tile = 768 blocks
    bt64x128_k<<<dim3(2 * DI / 128, NTOK / 64), 256, 0, stream>>>(
        h_bf, DM, in_w_bf + (size_t)l * 2 * DI * DM, DM, xz_bf, 2 * DI, DM);
    // conv + silu -> xc (bf16)
    conv_silu_k<<<dim3(DI / 512, SEQ / 16, BATCH), 256, 0, stream>>>(
        xz_bf, conv_w + (size_t)l * DI * 4, conv_b + (size_t)l * DI, xc_bf);
    // x_proj split-K (bf16 partials)
    xp_k<<<dim3(XKS, NTOK / 64), 256, 0, stream>>>(
        xc_bf, xp_w_bf + (size_t)l * DBC * DI, part_bf);
    xp_reduce_k<<<NTOK * DBC / 4 / 256, 256, 0, stream>>>(part_bf, dtA_bf, bc_bf);
    // dt_proj + softplus -> dtb (bf16)
    bt64_k<1><<<dim3(DI / 64, NTOK / 64), 256, 0, stream>>>(
        dtA_bf, 64, dtw_bf + (size_t)l * DI * 64, 64, dtb_bf, DI,
        64, dtp_b + (size_t)l * DI);
    // scan trio
    scan1_k<<<dim3(NCHUNK, 12), 256, 0, stream>>>(
        dtb_bf, xc_bf, bc_bf, negA + (size_t)l * DI * DS, ch_pk, yc_pk);
    scan2_k<<<192, 256, 0, stream>>>(
        ch_pk, hin, out_states + (size_t)l * BATCH * DI * DS);
    scanfix_k<<<NTOK * DI / 256, 256, 0, stream>>>(
        yc_pk, xc_bf, xz_bf, bc_bf, negA + (size_t)l * DI * DS,
        Dsk + (size_t)l * DI, hin, yb_bf);
    // out_proj split-K=2 -> fp32 partials
    bt64_k<3><<<dim3(DM / 64, NTOK / 64, 2), 256, 0, stream>>>(
        yb_bf, DI, out_w_bf + (size_t)l * DM * DI, DI, part2, DM,
        DI / 2, nullptr);
    // LN(part0+part1+resid) + adaln modulate
    ln_k<true><<<NTOK, 256, 0, stream>>>(
        part2, (l == 0) ? x : h_cur,
        norm_w + (size_t)l * DM, norm_b + (size_t)l * DM,
        ss + (size_t)l * BATCH * 2 * DM, h_cur, h_bf);
  }
  ln_k<false><<<NTOK, 256, 0, stream>>>(h_cur, nullptr, fn_w, fn_b, nullptr,
                                        out_h, nullptr);
}

// Round 15
// 698.077 us; speedup vs baseline: 1.0272x; 1.0272x over previous
//
#include <hip/hip_runtime.h>
#include <hip/hip_bf16.h>

#define NL 6
#define DM 768
#define DI 1536
#define DS 16
#define NRANK 48
#define DBC 80
#define BATCH 2
#define SEQ 1024
#define NTOK (BATCH*SEQ)
#define NCHUNK 64
#define CHLEN 16
#define XKS 8
#define XKC (DI/XKS)

typedef __attribute__((ext_vector_type(8))) short short8;
typedef __attribute__((ext_vector_type(8))) unsigned short ushort8v;
typedef __attribute__((ext_vector_type(4))) float f32x4;
typedef __attribute__((ext_vector_type(4))) unsigned short ushort4v;

__device__ inline unsigned short f2bf(float f) {
  union { float f; unsigned u; } x; x.f = f;
  unsigned r = x.u + 0x7FFF + ((x.u >> 16) & 1);
  return (unsigned short)(r >> 16);
}
__device__ inline float bf2f(unsigned short s) {
  union { unsigned u; float f; } x; x.u = ((unsigned)s) << 16;
  return x.f;
}

__device__ inline void gl_lds16(const unsigned short* g, unsigned short* l) {
  __builtin_amdgcn_global_load_lds(
      (const __attribute__((address_space(1))) unsigned int*)(g),
      (__attribute__((address_space(3))) unsigned int*)(l),
      16, 0, 0);
}

// convert ranges, unit = 8 elements; ADA tail unit = 1 element
#define V_X   (NTOK * DM / 8)
#define V_INW (NL * 2 * DI * DM / 8)
#define V_OUW (NL * DM * DI / 8)
#define V_XPW (NL * DBC * DI / 8)
#define V_DTW (NL * DI * 64 / 8)
#define V_NA  (NL * DI * DS / 8)
#define V_DTA (NTOK * 64 / 8)
#define V_ADA (NL * BATCH * 2 * DM)

__device__ inline ushort8v cvt8v(f32x4 a, f32x4 b) {
  union { ushort8v u8; __hip_bfloat162 h[4]; } u;
  float2 p;
  p.x = a[0]; p.y = a[1]; u.h[0] = __float22bfloat162_rn(p);
  p.x = a[2]; p.y = a[3]; u.h[1] = __float22bfloat162_rn(p);
  p.x = b[0]; p.y = b[1]; u.h[2] = __float22bfloat162_rn(p);
  p.x = b[2]; p.y = b[3]; u.h[3] = __float22bfloat162_rn(p);
  return u.u8;
}
__device__ inline void cvt8_store(const float* s, unsigned short* d, int i) {
  f32x4 a = ((const f32x4*)s)[i * 2];
  f32x4 b = ((const f32x4*)s)[i * 2 + 1];
  ((ushort8v*)d)[i] = cvt8v(a, b);
}

// streaming conversions + adaln matvec tail: branch-free per-region loops
__global__ __launch_bounds__(256) void cvt_k(
    const float* __restrict__ x, const float* __restrict__ inw,
    const float* __restrict__ ouw, const float* __restrict__ xpw,
    const float* __restrict__ dtpw, const float* __restrict__ alog,
    const float* __restrict__ cond, const float* __restrict__ adaw,
    const float* __restrict__ adab,
    unsigned short* __restrict__ xb, unsigned short* __restrict__ inwb,
    unsigned short* __restrict__ ouwb, unsigned short* __restrict__ xpwb,
    unsigned short* __restrict__ dtwb, float* __restrict__ na,
    unsigned short* __restrict__ dtA, float* __restrict__ ss) {
  const int gid = blockIdx.x * 256 + threadIdx.x;
  const int stride = gridDim.x * 256;
  for (int i = gid; i < V_X; i += stride) cvt8_store(x, xb, i);
  for (int i = gid; i < V_INW; i += stride) cvt8_store(inw, inwb, i);
  for (int i = gid; i < V_OUW; i += stride) cvt8_store(ouw, ouwb, i);
  for (int i = gid; i < V_XPW; i += stride) cvt8_store(xpw, xpwb, i);
  for (int i = gid; i < V_DTW; i += stride) {
    int col8 = (i & 7) * 8;
    int row = i >> 3;
    ushort8v u8;
    if (col8 < NRANK) {
      const float* src = dtpw + (size_t)row * NRANK + col8;
      f32x4 a = *(const f32x4*)src;
      f32x4 b = *(const f32x4*)(src + 4);
      u8 = cvt8v(a, b);
    } else {
      u8 = (ushort8v){0,0,0,0,0,0,0,0};
    }
    *(ushort8v*)&dtwb[(size_t)row * 64 + col8] = u8;
  }
  for (int i = gid; i < V_NA; i += stride) {
    f32x4 a = ((const f32x4*)alog)[i * 2];
    f32x4 b = ((const f32x4*)alog)[i * 2 + 1];
    f32x4 ra, rb;
#pragma unroll
    for (int e = 0; e < 4; e++) { ra[e] = -__expf(a[e]); rb[e] = -__expf(b[e]); }
    ((f32x4*)na)[i * 2] = ra;
    ((f32x4*)na)[i * 2 + 1] = rb;
  }
  for (int i = gid; i < V_DTA; i += stride)
    ((ushort8v*)dtA)[i] = (ushort8v){0,0,0,0,0,0,0,0};
  for (int i = gid; i < V_ADA; i += stride) {
    int e = i % (2 * DM);
    int b = (i / (2 * DM)) % BATCH;
    int l = i / (BATCH * 2 * DM);
    const float* c = cond + b * 128;
    const float* wp = adaw + ((size_t)l * (2 * DM) + e) * 128;
    float s = adab[l * (2 * DM) + e];
    for (int kk = 0; kk < 128; kk++) s = fmaf(c[kk], wp[kk], s);
    ss[i] = s;
  }
}

// ---------------------------------------------------------------------------
// 128x128-tile bf16 GEMM -> bf16 out. 3-stage counted-vmcnt pipeline.
// ---------------------------------------------------------------------------
__global__ __launch_bounds__(256) void bt128b_k(
    const unsigned short* __restrict__ A, int lda,
    const unsigned short* __restrict__ W, int ldw,
    unsigned short* __restrict__ C, int ldc,
    int K) {
  __shared__ __align__(16) unsigned short As[3][128 * 32];
  __shared__ __align__(16) unsigned short Ws[3][128 * 32];
  const int tid = threadIdx.x;
  const int bm = blockIdx.y * 128;
  const int bn = blockIdx.x * 128;
  const int lane = tid & 63;
  const int wv = tid >> 6;
  const int wm = (wv >> 1) * 64;
  const int wn = (wv & 1) * 64;
  const int fr = lane & 15;
  const int fs = lane >> 4;

  const int r0 = tid >> 2;
  const int s0 = (tid & 3) ^ (r0 & 3);

  const unsigned short* gA0 = A + (size_t)(bm + r0) * lda + s0 * 8;
  const unsigned short* gA1 = A + (size_t)(bm + r0 + 64) * lda + s0 * 8;
  const unsigned short* gW0 = W + (size_t)(bn + r0) * ldw + s0 * 8;
  const unsigned short* gW1 = W + (size_t)(bn + r0 + 64) * ldw + s0 * 8;

  f32x4 acc[4][4];
#pragma unroll
  for (int i = 0; i < 4; i++)
#pragma unroll
    for (int j = 0; j < 4; j++) acc[i][j] = (f32x4){0.f, 0.f, 0.f, 0.f};

  const int nk = K >> 5;
  gl_lds16(gA0, &As[0][0] + tid * 8);
  gl_lds16(gA1, &As[0][2048] + tid * 8);
  gl_lds16(gW0, &Ws[0][0] + tid * 8);
  gl_lds16(gW1, &Ws[0][2048] + tid * 8);
  if (nk > 1) {
    gl_lds16(gA0 + 32, &As[1][0] + tid * 8);
    gl_lds16(gA1 + 32, &As[1][2048] + tid * 8);
    gl_lds16(gW0 + 32, &Ws[1][0] + tid * 8);
    gl_lds16(gW1 + 32, &Ws[1][2048] + tid * 8);
  }

  for (int kk = 0; kk < nk; kk++) {
    const int b = kk % 3;
    if (kk + 2 < nk) {
      const int k0 = (kk + 2) * 32;
      const int nb = (kk + 2) % 3;
      gl_lds16(gA0 + k0, &As[nb][0] + tid * 8);
      gl_lds16(gA1 + k0, &As[nb][2048] + tid * 8);
      gl_lds16(gW0 + k0, &Ws[nb][0] + tid * 8);
      gl_lds16(gW1 + k0, &Ws[nb][2048] + tid * 8);
    }
    const int ahead = (nk - 1 - kk >= 2) ? 2 : (nk - 1 - kk);
    if (ahead == 2)      asm volatile("s_waitcnt vmcnt(8)" : : : "memory");
    else if (ahead == 1) asm volatile("s_waitcnt vmcnt(4)" : : : "memory");
    else                 asm volatile("s_waitcnt vmcnt(0)" : : : "memory");
    __builtin_amdgcn_s_barrier();
    __builtin_amdgcn_sched_barrier(0);

    short8 af[4], bf[4];
#pragma unroll
    for (int i = 0; i < 4; i++) {
      int rowa = wm + i * 16 + fr;
      af[i] = *(const short8*)&As[b][rowa * 32 + ((fs ^ (rowa & 3)) * 8)];
      int rowb = wn + i * 16 + fr;
      bf[i] = *(const short8*)&Ws[b][rowb * 32 + ((fs ^ (rowb & 3)) * 8)];
    }
#pragma unroll
    for (int i = 0; i < 4; i++)
#pragma unroll
      for (int j = 0; j < 4; j++)
        acc[i][j] = __builtin_amdgcn_mfma_f32_16x16x32_bf16(af[i], bf[j], acc[i][j], 0, 0, 0);

    __builtin_amdgcn_s_barrier();
  }

#pragma unroll
  for (int i = 0; i < 4; i++) {
#pragma unroll
    for (int j = 0; j < 4; j++) {
#pragma unroll
      for (int r = 0; r < 4; r++) {
        int row = bm + wm + i * 16 + fs * 4 + r;
        int col = bn + wn + j * 16 + fr;
        C[(size_t)row * ldc + col] = f2bf(acc[i][j][r]);
      }
    }
  }
}

// ---------------------------------------------------------------------------
// 64x64-tile bf16 GEMM, 3-stage pipeline.
// EPI 1: softplus(v+bias)->bf16. EPI 3: fp32 partial at [z*NTOK+row] (split-K).
// ---------------------------------------------------------------------------
template<int EPI>
__global__ __launch_bounds__(256) void bt64_k(
    const unsigned short* __restrict__ A, int lda,
    const unsigned short* __restrict__ W, int ldw,
    void* __restrict__ Cv, int ldc,
    int K,
    const float* __restrict__ bias) {
  __shared__ __align__(16) unsigned short As[3][64 * 32];
  __shared__ __align__(16) unsigned short Ws[3][64 * 32];
  const int tid = threadIdx.x;
  const int bm = blockIdx.y * 64;
  const int bn = blockIdx.x * 64;
  const int kz = (EPI == 3) ? blockIdx.z : 0;
  const int lane = tid & 63;
  const int wv = tid >> 6;
  const int wm = (wv >> 1) * 32;
  const int wn = (wv & 1) * 32;
  const int fr = lane & 15;
  const int fs = lane >> 4;

  const int r0 = tid >> 2;
  const int s0 = (tid & 3) ^ (r0 & 3);

  const unsigned short* gA = A + (size_t)(bm + r0) * lda + kz * K + s0 * 8;
  const unsigned short* gW = W + (size_t)(bn + r0) * ldw + kz * K + s0 * 8;

  f32x4 acc[2][2];
#pragma unroll
  for (int i = 0; i < 2; i++)
#pragma unroll
    for (int j = 0; j < 2; j++) acc[i][j] = (f32x4){0.f, 0.f, 0.f, 0.f};

  const int nk = K >> 5;
  gl_lds16(gA, &As[0][0] + tid * 8);
  gl_lds16(gW, &Ws[0][0] + tid * 8);
  if (nk > 1) {
    gl_lds16(gA + 32, &As[1][0] + tid * 8);
    gl_lds16(gW + 32, &Ws[1][0] + tid * 8);
  }

  for (int kk = 0; kk < nk; kk++) {
    const int b = kk % 3;
    if (kk + 2 < nk) {
      const int k0 = (kk + 2) * 32;
      const int nb = (kk + 2) % 3;
      gl_lds16(gA + k0, &As[nb][0] + tid * 8);
      gl_lds16(gW + k0, &Ws[nb][0] + tid * 8);
    }
    const int ahead = (nk - 1 - kk >= 2) ? 2 : (nk - 1 - kk);
    if (ahead == 2)      asm volatile("s_waitcnt vmcnt(4)" : : : "memory");
    else if (ahead == 1) asm volatile("s_waitcnt vmcnt(2)" : : : "memory");
    else                 asm volatile("s_waitcnt vmcnt(0)" : : : "memory");
    __builtin_amdgcn_s_barrier();
    __builtin_amdgcn_sched_barrier(0);

    short8 af[2], bf[2];
#pragma unroll
    for (int i = 0; i < 2; i++) {
      int rowa = wm + i * 16 + fr;
      af[i] = *(const short8*)&As[b][rowa * 32 + ((fs ^ (rowa & 3)) * 8)];
      int rowb = wn + i * 16 + fr;
      bf[i] = *(const short8*)&Ws[b][rowb * 32 + ((fs ^ (rowb & 3)) * 8)];
    }
#pragma unroll
    for (int i = 0; i < 2; i++)
#pragma unroll
      for (int j = 0; j < 2; j++)
        acc[i][j] = __builtin_amdgcn_mfma_f32_16x16x32_bf16(af[i], bf[j], acc[i][j], 0, 0, 0);

    __builtin_amdgcn_s_barrier();
  }

#pragma unroll
  for (int i = 0; i < 2; i++) {
#pragma unroll
    for (int j = 0; j < 2; j++) {
#pragma unroll
      for (int r = 0; r < 4; r++) {
        int row = bm + wm + i * 16 + fs * 4 + r;
        int col = bn + wn + j * 16 + fr;
        float v = acc[i][j][r];
        if (EPI == 1) {
          float xv = v + bias[col];
          float sp = (xv > 20.f) ? xv : log1pf(__expf(xv));
          ((unsigned short*)Cv)[(size_t)row * ldc + col] = f2bf(sp);
        }
        if (EPI == 3) {
          ((float*)Cv)[((size_t)kz * NTOK + row) * ldc + col] = v;
        }
      }
    }
  }
}

// ---------------------------------------------------------------------------
// x_proj split-K, bf16 in, bf16 partials out
// ---------------------------------------------------------------------------
__global__ __launch_bounds__(256) void xp_k(
    const unsigned short* __restrict__ A,
    const unsigned short* __restrict__ W,
    unsigned short* __restrict__ part) {
  __shared__ __align__(16) unsigned short As[64][40];
  __shared__ __align__(16) unsigned short Ws[80][40];
  const int tid = threadIdx.x;
  const int ks = blockIdx.x;
  const int bm = blockIdx.y * 64;
  const int lane = tid & 63;
  const int wv = tid >> 6;
  const int fr = lane & 15;
  const int fs = lane >> 4;
  const int fk = fs * 8;

  const int ar = tid >> 2;
  const int ac = (tid & 3) * 8;
  const int k0base = ks * XKC;

  const unsigned short* gA  = A + (size_t)(bm + ar) * DI + k0base + ac;
  const unsigned short* gW0 = W + (size_t)ar * DI + k0base + ac;
  const unsigned short* gW1 = W + (size_t)(64 + ar) * DI + k0base + ac;

  f32x4 acc[5];
#pragma unroll
  for (int n = 0; n < 5; n++) acc[n] = (f32x4){0.f, 0.f, 0.f, 0.f};

  short8 aA, w0A, w1A;
  aA = *(const short8*)(gA);
  w0A = *(const short8*)(gW0);
  if (tid < 64) w1A = *(const short8*)(gW1);

  const int nk = XKC / 32;
  for (int kk = 0; kk < nk; kk++) {
    __syncthreads();
    *(short8*)&As[ar][ac] = aA;
    *(short8*)&Ws[ar][ac] = w0A;
    if (tid < 64) *(short8*)&Ws[64 + ar][ac] = w1A;
    __syncthreads();

    if (kk + 1 < nk) {
      const int k0 = (kk + 1) * 32;
      aA = *(const short8*)(gA + k0);
      w0A = *(const short8*)(gW0 + k0);
      if (tid < 64) w1A = *(const short8*)(gW1 + k0);
    }

    short8 af = *(const short8*)&As[wv * 16 + fr][fk];
#pragma unroll
    for (int n = 0; n < 5; n++) {
      short8 bf = *(const short8*)&Ws[n * 16 + fr][fk];
      acc[n] = __builtin_amdgcn_mfma_f32_16x16x32_bf16(af, bf, acc[n], 0, 0, 0);
    }
  }

#pragma unroll
  for (int n = 0; n < 5; n++) {
#pragma unroll
    for (int r = 0; r < 4; r++) {
      int row = bm + wv * 16 + fs * 4 + r;
      part[((size_t)ks * NTOK + row) * DBC + n * 16 + fr] = f2bf(acc[n][r]);
    }
  }
}

// sum XKS bf16 partials -> dtA bf16 (cols 0..47) / bc bf16 (cols 48..79 -> 0..31)
__global__ __launch_bounds__(256) void xp_reduce_k(const unsigned short* __restrict__ part,
                                                   unsigned short* __restrict__ dtA,
                                                   unsigned short* __restrict__ bc) {
  int i = blockIdx.x * 256 + threadIdx.x;
  const ushort4v* p4 = (const ushort4v*)part;
  const int stride4 = NTOK * DBC / 4;
  float s0 = 0.f, s1 = 0.f, s2 = 0.f, s3 = 0.f;
#pragma unroll
  for (int ks = 0; ks < XKS; ks++) {
    ushort4v v = p4[(size_t)ks * stride4 + i];
    s0 += bf2f(v[0]); s1 += bf2f(v[1]); s2 += bf2f(v[2]); s3 += bf2f(v[3]);
  }
  ushort4v o;
  o[0] = f2bf(s0); o[1] = f2bf(s1); o[2] = f2bf(s2); o[3] = f2bf(s3);
  int c4 = (i * 4) % DBC;
  int m = (i * 4) / DBC;
  if (c4 < NRANK) {
    *(ushort4v*)&dtA[(size_t)m * 64 + c4] = o;
  } else {
    *(ushort4v*)&bc[(size_t)m * 32 + (c4 - NRANK)] = o;
  }
}

// depthwise causal conv(4) + bias + silu, register-carry, ushort2 vectorized
__global__ __launch_bounds__(256) void conv_silu_k(const unsigned short* __restrict__ xz,
                                                   const float* __restrict__ cw,
                                                   const float* __restrict__ cb,
                                                   unsigned short* __restrict__ xcb) {
  const int d0 = (blockIdx.x * 256 + threadIdx.x) * 2;
  const int l0 = blockIdx.y * 16;
  const int b = blockIdx.z;
  const size_t mbase = (size_t)b * SEQ;
  const float wa0 = cw[d0 * 4 + 0], wa1 = cw[d0 * 4 + 1];
  const float wa2 = cw[d0 * 4 + 2], wa3 = cw[d0 * 4 + 3];
  const float wb0 = cw[d0 * 4 + 4], wb1 = cw[d0 * 4 + 5];
  const float wb2 = cw[d0 * 4 + 6], wb3 = cw[d0 * 4 + 7];
  const float ba = cb[d0], bb = cb[d0 + 1];

  float a3 = 0.f, a2 = 0.f, a1 = 0.f, b3 = 0.f, b2 = 0.f, b1 = 0.f;
  if (l0 >= 3) { ushort2 u = *(const ushort2*)&xz[(mbase + l0 - 3) * (2 * DI) + d0]; a3 = bf2f(u.x); b3 = bf2f(u.y); }
  if (l0 >= 2) { ushort2 u = *(const ushort2*)&xz[(mbase + l0 - 2) * (2 * DI) + d0]; a2 = bf2f(u.x); b2 = bf2f(u.y); }
  if (l0 >= 1) { ushort2 u = *(const ushort2*)&xz[(mbase + l0 - 1) * (2 * DI) + d0]; a1 = bf2f(u.x); b1 = bf2f(u.y); }
#pragma unroll
  for (int t = 0; t < 16; t++) {
    const int l = l0 + t;
    ushort2 u = *(const ushort2*)&xz[(mbase + l) * (2 * DI) + d0];
    float ca = bf2f(u.x), cbv = bf2f(u.y);
    float sa = ba + wa0 * a3 + wa1 * a2 + wa2 * a1 + wa3 * ca;
    float sb = bb + wb0 * b3 + wb1 * b2 + wb2 * b1 + wb3 * cbv;
    float ra = sa / (1.f + __expf(-sa));
    float rb = sb / (1.f + __expf(-sb));
    ushort2 o; o.x = f2bf(ra); o.y = f2bf(rb);
    *(ushort2*)&xcb[(mbase + l) * DI + d0] = o;
    a3 = a2; a2 = a1; a1 = ca;
    b3 = b2; b2 = b1; b1 = cbv;
  }
}

// ---------------------------------------------------------------------------
// scan pass 1
// ---------------------------------------------------------------------------
__global__ __launch_bounds__(256) void scan1_k(const unsigned short* __restrict__ dt,
                                               const unsigned short* __restrict__ xc,
                                               const unsigned short* __restrict__ bc,
                                               const float* __restrict__ negA_l,
                                               unsigned int* __restrict__ ch_pk,
                                               unsigned int* __restrict__ yc_pk) {
  __shared__ float Bs[CHLEN][DS];
  __shared__ float Cs[CHLEN][DS];
  const int tid = threadIdx.x;
  const int j = blockIdx.x;
  const int cg = blockIdx.y;
  const int b = cg / 6;
  const int d = (cg % 6) * 256 + tid;
  const int c = b * DI + d;
  const int m0 = b * SEQ + j * CHLEN;

  for (int e = tid; e < CHLEN * 32; e += 256) {
    int row = e >> 5, col = e & 31;
    float v = bf2f(bc[(size_t)(m0 + row) * 32 + col]);
    if (col < DS) Bs[row][col] = v; else Cs[row][col - DS] = v;
  }

  float Av[DS];
  const float* na = negA_l + (size_t)d * DS;
#pragma unroll
  for (int s = 0; s < DS; s++) Av[s] = na[s];
  const float Av0 = Av[0];
  bool fast = true;
#pragma unroll
  for (int s = 0; s < DS; s++)
    fast = fast && (fabsf(Av[s] - (s + 1) * Av0) <= 1e-4f * (s + 1));

  float dts[CHLEN], xcs[CHLEN];
#pragma unroll
  for (int t = 0; t < CHLEN; t++) {
    dts[t] = bf2f(dt[(size_t)(m0 + t) * DI + d]);
    xcs[t] = bf2f(xc[(size_t)(m0 + t) * DI + d]);
  }
  __syncthreads();

  float h[DS];
#pragma unroll
  for (int s = 0; s < DS; s++) h[s] = 0.f;
  float cd = 0.f;

  for (int t = 0; t < CHLEN; t++) {
    float dtv = dts[t];
    cd += dtv;
    float dtx = dtv * xcs[t];
    float ysum = 0.f;
    if (fast) {
      float e1 = __expf(dtv * Av0);
      float dA = e1;
      h[0] = fmaf(dA, h[0], dtx * Bs[t][0]);
      ysum = fmaf(h[0], Cs[t][0], ysum);
#pragma unroll
      for (int s = 1; s < DS; s++) {
        dA *= e1;
        h[s] = fmaf(dA, h[s], dtx * Bs[t][s]);
        ysum = fmaf(h[s], Cs[t][s], ysum);
      }
    } else {
#pragma unroll
      for (int s = 0; s < DS; s++) {
        float dA = __expf(dtv * Av[s]);
        h[s] = fmaf(dA, h[s], dtx * Bs[t][s]);
        ysum = fmaf(h[s], Cs[t][s], ysum);
      }
    }
    yc_pk[(size_t)(m0 + t) * DI + d] =
        (unsigned int)f2bf(ysum) | ((unsigned int)f2bf(cd) << 16);
  }

  size_t base = ((size_t)j * (BATCH * DI) + c) * DS;
#pragma unroll
  for (int s = 0; s < DS; s++) {
    unsigned int pk = (unsigned int)f2bf(__expf(cd * Av[s]))
                    | ((unsigned int)f2bf(h[s]) << 16);
    ch_pk[base + s] = pk;
  }
}

// pass 2: sequential chunk combine, 8-wide load batching
__global__ __launch_bounds__(256) void scan2_k(const unsigned int* __restrict__ ch_pk,
                                               unsigned short* __restrict__ hin,
                                               float* __restrict__ states_out) {
  int idx = blockIdx.x * 256 + threadIdx.x;
  const int stride = BATCH * DI * DS;
  float h = 0.f;
  for (int g = 0; g < NCHUNK / 8; g++) {
    unsigned int pks[8];
#pragma unroll
    for (int u = 0; u < 8; u++)
      pks[u] = ch_pk[(size_t)(g * 8 + u) * stride + idx];
#pragma unroll
    for (int u = 0; u < 8; u++) {
      hin[(size_t)(g * 8 + u) * stride + idx] = f2bf(h);
      h = fmaf(bf2f((unsigned short)(pks[u] & 0xFFFF)), h,
               bf2f((unsigned short)(pks[u] >> 16)));
    }
  }
  states_out[idx] = h;
}

// pass 3: parallel fixup
__global__ __launch_bounds__(256) void scanfix_k(const unsigned int* __restrict__ yc_pk,
                                                 const unsigned short* __restrict__ xc,
                                                 const unsigned short* __restrict__ xz,
                                                 const unsigned short* __restrict__ bc,
                                                 const float* __restrict__ negA_l,
                                                 const float* __restrict__ Dsk,
                                                 const unsigned short* __restrict__ hin,
                                                 unsigned short* __restrict__ y) {
  int idx = blockIdx.x * 256 + threadIdx.x;
  int d = idx % DI;
  int m = idx / DI;
  int b = m / SEQ;
  int j = (m % SEQ) / CHLEN;
  unsigned int pk = yc_pk[idx];
  float yv = bf2f((unsigned short)(pk & 0xFFFF));
  float cd = bf2f((unsigned short)(pk >> 16));
  const f32x4* na4 = (const f32x4*)(negA_l + (size_t)d * DS);
  const ushort4v* cp4 = (const ushort4v*)(bc + (size_t)m * 32 + DS);
  const ushort4v* h4 = (const ushort4v*)(hin + ((size_t)j * (BATCH * DI) + (size_t)b * DI + d) * DS);
  float corr = 0.f;
#pragma unroll
  for (int q = 0; q < 4; q++) {
    f32x4 na = na4[q];
    ushort4v cp = cp4[q];
    ushort4v hh = h4[q];
#pragma unroll
    for (int e = 0; e < 4; e++)
      corr = fmaf(__expf(cd * na[e]) * bf2f(hh[e]), bf2f(cp[e]), corr);
  }
  yv += corr;
  float xv = bf2f(xc[idx]);
  float zv = bf2f(xz[(size_t)m * (2 * DI) + DI + d]);
  float sig = 1.f / (1.f + __expf(-zv));
  y[idx] = f2bf((yv + Dsk[d] * xv) * (zv * sig));
}

// LN. ADA=true: input = part[0]+part[1]+resid, LN -> LN_noaffine -> modulate.
template<bool ADA>
__global__ __launch_bounds__(256) void ln_k(const float* __restrict__ in,
                                            const float* __restrict__ resid,
                                            const float* __restrict__ w,
                                            const float* __restrict__ bb,
                                            const float* __restrict__ ss,
                                            float* __restrict__ out,
                                            unsigned short* __restrict__ outb) {
  __shared__ float red[8];
  const int row = blockIdx.x;
  const int bt = row / SEQ;
  const int tid = threadIdx.x;
  float v[3];
#pragma unroll
  for (int i = 0; i < 3; i++) {
    int c = tid + i * 256;
    if (ADA) {
      v[i] = in[(size_t)row * DM + c] + in[(size_t)(NTOK + row) * DM + c]
           + resid[(size_t)row * DM + c];
    } else {
      v[i] = in[(size_t)row * DM + c];
    }
  }
  float s1 = v[0] + v[1] + v[2];
  float s2 = v[0]*v[0] + v[1]*v[1] + v[2]*v[2];
#pragma unroll
  for (int o = 32; o > 0; o >>= 1) { s1 += __shfl_down(s1, o); s2 += __shfl_down(s2, o); }
  int wv = tid >> 6, ln = tid & 63;
  if (ln == 0) { red[wv*2] = s1; red[wv*2+1] = s2; }
  __syncthreads();
  s1 = red[0] + red[2] + red[4] + red[6];
  s2 = red[1] + red[3] + red[5] + red[7];
  float mu = s1 * (1.f / DM);
  float var = s2 * (1.f / DM) - mu * mu;
  float rs = rsqrtf(var + 1e-5f);
  float t[3];
#pragma unroll
  for (int i = 0; i < 3; i++) {
    int c = tid + i * 256;
    t[i] = (v[i] - mu) * rs * w[c] + bb[c];
  }
  if (!ADA) {
#pragma unroll
    for (int i = 0; i < 3; i++) out[(size_t)row * DM + tid + i * 256] = t[i];
    return;
  }
  __syncthreads();
  s1 = t[0] + t[1] + t[2];
  s2 = t[0]*t[0] + t[1]*t[1] + t[2]*t[2];
#pragma unroll
  for (int o = 32; o > 0; o >>= 1) { s1 += __shfl_down(s1, o); s2 += __shfl_down(s2, o); }
  if (ln == 0) { red[wv*2] = s1; red[wv*2+1] = s2; }
  __syncthreads();
  s1 = red[0] + red[2] + red[4] + red[6];
  s2 = red[1] + red[3] + red[5] + red[7];
  float mu2 = s1 * (1.f / DM);
  float var2 = s2 * (1.f / DM) - mu2 * mu2;
  float rs2 = rsqrtf(var2 + 1e-5f);
#pragma unroll
  for (int i = 0; i < 3; i++) {
    int c = tid + i * 256;
    float sc = ss[bt * (2 * DM) + c];
    float sh = ss[bt * (2 * DM) + DM + c];
    float r = (t[i] - mu2) * rs2 * (1.f + sc) + sh;
    out[(size_t)row * DM + c] = r;
    outb[(size_t)row * DM + c] = f2bf(r);
  }
}

extern "C" void kernel_launch(void* const* d_in, const int* in_sizes, int n_in,
                              void* d_out, int out_size, void* d_ws, size_t ws_size,
                              hipStream_t stream) {
  const float* x      = (const float*)d_in[0];
  const float* cond   = (const float*)d_in[1];
  const float* in_w   = (const float*)d_in[2];
  const float* conv_w = (const float*)d_in[3];
  const float* conv_b = (const float*)d_in[4];
  const float* xp_w   = (const float*)d_in[5];
  const float* dtp_w  = (const float*)d_in[6];
  const float* dtp_b  = (const float*)d_in[7];
  const float* A_log  = (const float*)d_in[8];
  const float* Dsk    = (const float*)d_in[9];
  const float* out_w  = (const float*)d_in[10];
  const float* norm_w = (const float*)d_in[11];
  const float* norm_b = (const float*)d_in[12];
  const float* ada_w  = (const float*)d_in[13];
  const float* ada_b  = (const float*)d_in[14];
  const float* fn_w   = (const float*)d_in[15];
  const float* fn_b   = (const float*)d_in[16];

  float* out_h = (float*)d_out;
  float* out_states = out_h + (size_t)NTOK * DM;

  float* p = (float*)d_ws;
  float* h_cur = p; p += (size_t)NTOK * DM;
  float* part2 = p; p += (size_t)2 * NTOK * DM;
  float* ss    = p; p += (size_t)NL * BATCH * 2 * DM;
  float* negA  = p; p += (size_t)NL * DI * DS;
  unsigned int* ch_pk = (unsigned int*)p; p += (size_t)NCHUNK * BATCH * DI * DS;
  unsigned int* yc_pk = (unsigned int*)p; p += (size_t)NTOK * DI;
  unsigned short* q = (unsigned short*)p;
  unsigned short* hin      = q; q += (size_t)NCHUNK * BATCH * DI * DS;
  unsigned short* in_w_bf  = q; q += (size_t)NL * 2 * DI * DM;
  unsigned short* out_w_bf = q; q += (size_t)NL * DM * DI;
  unsigned short* xp_w_bf  = q; q += (size_t)NL * DBC * DI;
  unsigned short* dtw_bf   = q; q += (size_t)NL * DI * 64;
  unsigned short* h_bf     = q; q += (size_t)NTOK * DM;
  unsigned short* xz_bf    = q; q += (size_t)NTOK * 2 * DI;
  unsigned short* xc_bf    = q; q += (size_t)NTOK * DI;
  unsigned short* dtb_bf   = q; q += (size_t)NTOK * DI;
  unsigned short* yb_bf    = q; q += (size_t)NTOK * DI;
  unsigned short* part_bf  = q; q += (size_t)XKS * NTOK * DBC;
  unsigned short* dtA_bf   = q; q += (size_t)NTOK * 64;
  unsigned short* bc_bf    = q; q += (size_t)NTOK * 32;

  cvt_k<<<2048, 256, 0, stream>>>(x, in_w, out_w, xp_w, dtp_w, A_log,
                                  cond, ada_w, ada_b,
                                  h_bf, in_w_bf, out_w_bf, xp_w_bf, dtw_bf,
                                  negA, dtA_bf, ss);

  for (int l = 0; l < NL; l++) {
    // in_proj -> xz (bf16), 128x128 tile
    bt128b_k<<<dim3(24, 16), 256, 0, stream>>>(
        h_bf, DM, in_w_bf + (size_t)l * 2 * DI * DM, DM, xz_bf, 2 * DI, DM);
    // conv + silu -> xc (bf16)
    conv_silu_k<<<dim3(DI / 512, SEQ / 16, BATCH), 256, 0, stream>>>(
        xz_bf, conv_w + (size_t)l * DI * 4, conv_b + (size_t)l * DI, xc_bf);
    // x_proj split-K (bf16 partials)
    xp_k<<<dim3(XKS, NTOK / 64), 256, 0, stream>>>(
        xc_bf, xp_w_bf + (size_t)l * DBC * DI, part_bf);
    xp_reduce_k<<<NTOK * DBC / 4 / 256, 256, 0, stream>>>(part_bf, dtA_bf, bc_bf);
    // dt_proj + softplus -> dtb (bf16)
    bt64_k<1><<<dim3(DI / 64, NTOK / 64), 256, 0, stream>>>(
        dtA_bf, 64, dtw_bf + (size_t)l * DI * 64, 64, dtb_bf, DI,
        64, dtp_b + (size_t)l * DI);
    // scan trio
    scan1_k<<<dim3(NCHUNK, 12), 256, 0, stream>>>(
        dtb_bf, xc_bf, bc_bf, negA + (size_t)l * DI * DS, ch_pk, yc_pk);
    scan2_k<<<192, 256, 0, stream>>>(
        ch_pk, hin, out_states + (size_t)l * BATCH * DI * DS);
    scanfix_k<<<NTOK * DI / 256, 256, 0, stream>>>(
        yc_pk, xc_bf, xz_bf, bc_bf, negA + (size_t)l * DI * DS,
        Dsk + (size_t)l * DI, hin, yb_bf);
    // out_proj split-K=2 -> fp32 partials
    bt64_k<3><<<dim3(DM / 64, NTOK / 64, 2), 256, 0, stream>>>(
        yb_bf, DI, out_w_bf + (size_t)l * DM * DI, DI, part2, DM,
        DI / 2, nullptr);
    // LN(part0+part1+resid) + adaln modulate
    ln_k<true><<<NTOK, 256, 0, stream>>>(
        part2, (l == 0) ? x : h_cur,
        norm_w + (size_t)l * DM, norm_b + (size_t)l * DM,
        ss + (size_t)l * BATCH * 2 * DM, h_cur, h_bf);
  }
  ln_k<false><<<NTOK, 256, 0, stream>>>(h_cur, nullptr, fn_w, fn_b, nullptr,
                                        out_h, nullptr);
}